// Round 6
// baseline (86.004 us; speedup 1.0000x reference)
//
#include <hip/hip_runtime.h>

#define BLOCK 256
#define SPLITS 16
#define QPT 8
#define PREPT 1024

// d2(q,c) = q2 + (c2 - 2qx*cx - 2qy*cy); all terms integer-valued fp32 < 2^24
// for valid candidates -> exact. Sentinel (3e4): value ~1.7e9 >> any valid d2
// (<= 5.3e5); after sqrt*0.01 -> ~417 >> max real output 7.25, never wins the
// min when gate==1 (count>=2 implies a real candidate exists somewhere).

// ws layout: [0] int gate | [256B] float wx[mPad] | [256B+mPad*4] float wy[mPad]

__global__ __launch_bounds__(PREPT) void prep_kernel(
    const float* __restrict__ pts, const int* __restrict__ vox,
    int m, int mPad,
    int* __restrict__ gate, float* __restrict__ wx, float* __restrict__ wy,
    int* __restrict__ out_bits, int total)
{
    __shared__ int s_cnt;
    if (threadIdx.x == 0) s_cnt = 0;
    __syncthreads();

    int nv = 0;
    for (int i = threadIdx.x; i < mPad; i += PREPT) {
        float x = 3.0e4f, y = 3.0e4f;
        if (i < m && fabsf(pts[i * 5 + 4]) > 0.1f) {
            x = (float)vox[i * 3 + 1];
            y = (float)vox[i * 3 + 2];
            nv++;
        }
        wx[i] = x;
        wy[i] = y;
    }
    if (nv) atomicAdd(&s_cnt, nv);

    // Init out to large positive float bits (0x7F7F7F7F ~ 3.39e38) so
    // atomicMin-as-int works for the non-negative final values.
    const int4 iv = make_int4(0x7F7F7F7F, 0x7F7F7F7F, 0x7F7F7F7F, 0x7F7F7F7F);
    int4* o4 = (int4*)out_bits;
    const int n4 = total >> 2;                    // total divisible by 4
    for (int i = threadIdx.x; i < n4; i += PREPT) o4[i] = iv;

    __syncthreads();
    if (threadIdx.x == 0) *gate = (s_cnt > 1) ? 1 : 0;
}

__global__ __launch_bounds__(BLOCK) void main_kernel(
    const int* __restrict__ li_coors, int n_li,
    const int* __restrict__ ra_coors, int n_ra,
    const float* __restrict__ wx, const float* __restrict__ wy,
    const int* __restrict__ gate, int cs,
    int* __restrict__ out_bits, int total)
{
    const int split = blockIdx.y;
    const int li_total = n_li * 9;
    const int qbase = blockIdx.x * (BLOCK * QPT) + threadIdx.x;

    float n2x[QPT], n2y[QPT], q2[QPT], mn[QPT];
#pragma unroll
    for (int k = 0; k < QPT; ++k) {
        int q = qbase + k * BLOCK;
        float qx = 0.0f, qy = 0.0f;
        if (q < total) {
            const int shift_x[9] = {0,-1,1,0,-1,1,0,-1,1};
            const int shift_y[9] = {0, 0,0,1, 1,1,-1,-1,-1};
            int n, s;
            const int* src;
            if (q < li_total) { n = q / 9; s = q - n * 9; src = li_coors; }
            else { int r = q - li_total; n = r / 9; s = r - n * 9; src = ra_coors; }
            int cx = src[n * 2 + 0] + shift_x[s];
            int cy = src[n * 2 + 1] + shift_y[s];
            if (cx < 0) cx += 513;   // coords in [0,511], shift in {-1,0,1}
            if (cy < 0) cy += 513;
            qx = (float)cx; qy = (float)cy;
        }
        n2x[k] = -2.0f * qx;
        n2y[k] = -2.0f * qy;
        q2[k]  = fmaf(qx, qx, qy * qy);
        mn[k]  = 3.4e38f;
    }

    // 4 candidates per iter via two uniform-address float4 loads (1 KB chunk,
    // L1/SGPR-resident -> no LDS pipe pressure), amortized over 8 queries.
    const float4* __restrict__ X4 = (const float4*)(wx + split * cs);
    const float4* __restrict__ Y4 = (const float4*)(wy + split * cs);
    const int iters = cs >> 2;
    for (int i = 0; i < iters; ++i) {
        float4 X = X4[i];
        float4 Y = Y4[i];
        float c0 = fmaf(X.x, X.x, Y.x * Y.x);
        float c1 = fmaf(X.y, X.y, Y.y * Y.y);
        float c2 = fmaf(X.z, X.z, Y.z * Y.z);
        float c3 = fmaf(X.w, X.w, Y.w * Y.w);
#pragma unroll
        for (int k = 0; k < QPT; ++k) {
            float t0 = fmaf(X.x, n2x[k], fmaf(Y.x, n2y[k], c0));
            float t1 = fmaf(X.y, n2x[k], fmaf(Y.y, n2y[k], c1));
            float t2 = fmaf(X.z, n2x[k], fmaf(Y.z, n2y[k], c2));
            float t3 = fmaf(X.w, n2x[k], fmaf(Y.w, n2y[k], c3));
            mn[k] = fminf(fminf(t0, t1), mn[k]);   // v_min3
            mn[k] = fminf(fminf(t2, t3), mn[k]);   // v_min3
        }
    }

    const int g = *gate;
#pragma unroll
    for (int k = 0; k < QPT; ++k) {
        int q = qbase + k * BLOCK;
        if (q < total) {
            float d2 = q2[k] + mn[k];
            float val = g ? sqrtf(d2) * 0.01f : 0.0f;
            // min commutes with monotone sqrt/scale; bits-as-int min valid
            // for non-negative floats.
            atomicMin(out_bits + q, __float_as_int(val));
        }
    }
}

extern "C" void kernel_launch(void* const* d_in, const int* in_sizes, int n_in,
                              void* d_out, int out_size, void* d_ws, size_t ws_size,
                              hipStream_t stream) {
    const int*   li  = (const int*)d_in[0];
    const int*   ra  = (const int*)d_in[1];
    const float* pts = (const float*)d_in[2];
    const int*   vox = (const int*)d_in[3];

    const int n_li = in_sizes[0] / 2;
    const int n_ra = in_sizes[1] / 2;
    const int m    = in_sizes[2] / 5;

    const int total = (n_li + n_ra) * 9;                            // 92160
    const int qblocks = (total + BLOCK * QPT - 1) / (BLOCK * QPT);  // 45

    const int unit = SPLITS * 4;
    const int mPad = ((m + unit - 1) / unit) * unit;                // 2048
    const int cs   = mPad / SPLITS;                                 // 128

    int*   gate = (int*)d_ws;
    float* wx   = (float*)((char*)d_ws + 256);
    float* wy   = (float*)((char*)d_ws + 256 + (size_t)mPad * sizeof(float));
    int*   outb = (int*)d_out;

    prep_kernel<<<1, PREPT, 0, stream>>>(pts, vox, m, mPad, gate, wx, wy,
                                         outb, total);
    main_kernel<<<dim3(qblocks, SPLITS), BLOCK, 0, stream>>>(
        li, n_li, ra, n_ra, wx, wy, gate, cs, outb, total);
}

// Round 7
// 79.177 us; speedup vs baseline: 1.0862x; 1.0862x over previous
//
#include <hip/hip_runtime.h>

#define BLOCK 256
#define SPLITS 16
#define QPT 8
#define PREPB 90
#define MAXC 136   // padded chunk capacity (m<=2048 -> cs=128)

// d2(q,c) = q2 + (c2 - 2qx*cx - 2qy*cy); all terms integer-valued fp32 < 2^24
// for valid candidates -> exact. Sentinel (3e4): d2 ~1.7e9 >> any valid d2
// (<=5.3e5) -> never wins the min when gate==1. Hardware sqrt is monotone so
// min(sqrt(x)*0.01) == sqrt(min x)*0.01 (same op order as R6, absmax 0).

__global__ __launch_bounds__(BLOCK) void prep_kernel(
    const float* __restrict__ pts, int m,
    int* __restrict__ gate, int* __restrict__ out_bits, int total)
{
    __shared__ int s_cnt;
    // Init out to 0x7F7F7F7F (~3.39e38) so atomicMin-as-int works for the
    // non-negative final values. One int4 per thread covers total/4 ints.
    const int tid = blockIdx.x * BLOCK + threadIdx.x;
    const int n4 = total >> 2;
    const int4 iv = make_int4(0x7F7F7F7F, 0x7F7F7F7F, 0x7F7F7F7F, 0x7F7F7F7F);
    int4* o4 = (int4*)out_bits;
    for (int i = tid; i < n4; i += PREPB * BLOCK) o4[i] = iv;

    // Block 0: count dynamic candidates -> gate (tiny; 8 loads/thread).
    if (blockIdx.x == 0) {
        if (threadIdx.x == 0) s_cnt = 0;
        __syncthreads();
        int nv = 0;
        for (int i = threadIdx.x; i < m; i += BLOCK)
            nv += (fabsf(pts[i * 5 + 4]) > 0.1f) ? 1 : 0;
        if (nv) atomicAdd(&s_cnt, nv);
        __syncthreads();
        if (threadIdx.x == 0) *gate = (s_cnt > 1) ? 1 : 0;
    }
}

__global__ __launch_bounds__(BLOCK) void main_kernel(
    const int* __restrict__ li_coors, int n_li,
    const int* __restrict__ ra_coors, int n_ra,
    const float* __restrict__ pts,
    const int* __restrict__ vox,
    int m, int cs, int csPad,
    const int* __restrict__ gate,
    int* __restrict__ out_bits, int total)
{
    __shared__ __align__(16) float sx[MAXC];
    __shared__ __align__(16) float sy[MAXC];

    // Stage this split's candidate chunk (SoA; invalid/pad -> sentinel).
    const int base = blockIdx.y * cs;
    for (int i = threadIdx.x; i < csPad; i += BLOCK) {
        int gi = base + i;
        float x = 3.0e4f, y = 3.0e4f;
        if (i < cs && gi < m && fabsf(pts[gi * 5 + 4]) > 0.1f) {
            x = (float)vox[gi * 3 + 1];
            y = (float)vox[gi * 3 + 2];
        }
        sx[i] = x;
        sy[i] = y;
    }
    __syncthreads();

    const int li_total = n_li * 9;
    const int qbase = blockIdx.x * (BLOCK * QPT) + threadIdx.x;

    float n2x[QPT], n2y[QPT], q2[QPT], mn[QPT];
#pragma unroll
    for (int k = 0; k < QPT; ++k) {
        int q = qbase + k * BLOCK;
        float qx = 0.0f, qy = 0.0f;
        if (q < total) {
            const int shift_x[9] = {0,-1,1,0,-1,1,0,-1,1};
            const int shift_y[9] = {0, 0,0,1, 1,1,-1,-1,-1};
            int n, s;
            const int* src;
            if (q < li_total) { n = q / 9; s = q - n * 9; src = li_coors; }
            else { int r = q - li_total; n = r / 9; s = r - n * 9; src = ra_coors; }
            int cx = src[n * 2 + 0] + shift_x[s];
            int cy = src[n * 2 + 1] + shift_y[s];
            if (cx < 0) cx += 513;   // coords in [0,511], shift in {-1,0,1}
            if (cy < 0) cy += 513;
            qx = (float)cx; qy = (float)cy;
        }
        n2x[k] = -2.0f * qx;
        n2y[k] = -2.0f * qy;
        q2[k]  = fmaf(qx, qx, qy * qy);
        mn[k]  = 3.4e38f;
    }

    // 4 candidates/iter via 2x ds_read_b128, amortized over 8 queries.
    const float4* __restrict__ X4 = (const float4*)sx;
    const float4* __restrict__ Y4 = (const float4*)sy;
    const int iters = csPad >> 2;
#pragma unroll 4
    for (int i = 0; i < iters; ++i) {
        float4 X = X4[i];
        float4 Y = Y4[i];
        float c0 = fmaf(X.x, X.x, Y.x * Y.x);
        float c1 = fmaf(X.y, X.y, Y.y * Y.y);
        float c2 = fmaf(X.z, X.z, Y.z * Y.z);
        float c3 = fmaf(X.w, X.w, Y.w * Y.w);
#pragma unroll
        for (int k = 0; k < QPT; ++k) {
            float t0 = fmaf(X.x, n2x[k], fmaf(Y.x, n2y[k], c0));
            float t1 = fmaf(X.y, n2x[k], fmaf(Y.y, n2y[k], c1));
            float t2 = fmaf(X.z, n2x[k], fmaf(Y.z, n2y[k], c2));
            float t3 = fmaf(X.w, n2x[k], fmaf(Y.w, n2y[k], c3));
            mn[k] = fminf(fminf(t0, t1), mn[k]);   // v_min3
            mn[k] = fminf(fminf(t2, t3), mn[k]);   // v_min3
        }
    }

    const int g = *gate;
#pragma unroll
    for (int k = 0; k < QPT; ++k) {
        int q = qbase + k * BLOCK;
        if (q < total) {
            float val = g ? sqrtf(q2[k] + mn[k]) * 0.01f : 0.0f;
            atomicMin(out_bits + q, __float_as_int(val));
        }
    }
}

extern "C" void kernel_launch(void* const* d_in, const int* in_sizes, int n_in,
                              void* d_out, int out_size, void* d_ws, size_t ws_size,
                              hipStream_t stream) {
    const int*   li  = (const int*)d_in[0];
    const int*   ra  = (const int*)d_in[1];
    const float* pts = (const float*)d_in[2];
    const int*   vox = (const int*)d_in[3];

    const int n_li = in_sizes[0] / 2;
    const int n_ra = in_sizes[1] / 2;
    const int m    = in_sizes[2] / 5;

    const int total = (n_li + n_ra) * 9;                            // 92160
    const int qblocks = (total + BLOCK * QPT - 1) / (BLOCK * QPT);  // 45

    const int cs    = (m + SPLITS - 1) / SPLITS;                    // 128
    const int csPad = (cs + 3) & ~3;                                // <= MAXC

    int* gate = (int*)d_ws;
    int* outb = (int*)d_out;

    prep_kernel<<<PREPB, BLOCK, 0, stream>>>(pts, m, gate, outb, total);
    main_kernel<<<dim3(qblocks, SPLITS), BLOCK, 0, stream>>>(
        li, n_li, ra, n_ra, pts, vox, m, cs, csPad, gate, outb, total);
}

// Round 8
// 78.673 us; speedup vs baseline: 1.0932x; 1.0064x over previous
//
#include <hip/hip_runtime.h>

#define BLOCK 256
#define SPLITS 16
#define QPT 8
#define PREPB 90
#define MAXC 136   // padded chunk capacity (m<=2048 -> cs=128)

// d2(q,c) = q2 + (c2 - 2qx*cx - 2qy*cy); all terms integer-valued fp32 < 2^24
// for valid candidates -> exact. Sentinel (3e4): d2 ~1.7e9 >> any valid d2
// (<=5.3e5) -> never wins the min when gate==1. sqrt monotone => min commutes.

__device__ __forceinline__ float2 pk_fma2(float2 a, float2 b, float2 c) {
    return make_float2(fmaf(a.x, b.x, c.x), fmaf(a.y, b.y, c.y));
}
__device__ __forceinline__ float2 pk_mul2(float2 a, float2 b) {
    return make_float2(a.x * b.x, a.y * b.y);
}

__global__ __launch_bounds__(BLOCK) void prep_kernel(
    const float* __restrict__ pts, int m,
    int* __restrict__ gate, int* __restrict__ out_bits, int total)
{
    __shared__ int s_cnt;
    // Init out to 0x7F7F7F7F (~3.39e38) so atomicMin-as-int works for the
    // non-negative final values. One int4 per thread covers total/4 ints.
    const int tid = blockIdx.x * BLOCK + threadIdx.x;
    const int n4 = total >> 2;
    const int4 iv = make_int4(0x7F7F7F7F, 0x7F7F7F7F, 0x7F7F7F7F, 0x7F7F7F7F);
    int4* o4 = (int4*)out_bits;
    for (int i = tid; i < n4; i += PREPB * BLOCK) o4[i] = iv;

    if (blockIdx.x == 0) {
        if (threadIdx.x == 0) s_cnt = 0;
        __syncthreads();
        int nv = 0;
        for (int i = threadIdx.x; i < m; i += BLOCK)
            nv += (fabsf(pts[i * 5 + 4]) > 0.1f) ? 1 : 0;
        if (nv) atomicAdd(&s_cnt, nv);
        __syncthreads();
        if (threadIdx.x == 0) *gate = (s_cnt > 1) ? 1 : 0;
    }
}

__global__ __launch_bounds__(BLOCK) void main_kernel(
    const int* __restrict__ li_coors, int n_li,
    const int* __restrict__ ra_coors, int n_ra,
    const float* __restrict__ pts,
    const int* __restrict__ vox,
    int m, int cs, int csPad,
    const int* __restrict__ gate,
    int* __restrict__ out_bits, int total)
{
    __shared__ __align__(16) float sx[MAXC];
    __shared__ __align__(16) float sy[MAXC];

    const int g = *gate;   // scalar load, hoisted; latency hidden by the loop

    // Query decode first: scattered global loads overlap the staging below.
    const int li_total = n_li * 9;
    const int qbase = blockIdx.x * (BLOCK * QPT) + threadIdx.x;

    float n2x[QPT], n2y[QPT], q2[QPT], mn[QPT];
#pragma unroll
    for (int k = 0; k < QPT; ++k) {
        int q = qbase + k * BLOCK;
        float qx = 0.0f, qy = 0.0f;
        if (q < total) {
            const int shift_x[9] = {0,-1,1,0,-1,1,0,-1,1};
            const int shift_y[9] = {0, 0,0,1, 1,1,-1,-1,-1};
            int n, s;
            const int* src;
            if (q < li_total) { n = q / 9; s = q - n * 9; src = li_coors; }
            else { int r = q - li_total; n = r / 9; s = r - n * 9; src = ra_coors; }
            int cx = src[n * 2 + 0] + shift_x[s];
            int cy = src[n * 2 + 1] + shift_y[s];
            if (cx < 0) cx += 513;   // coords in [0,511], shift in {-1,0,1}
            if (cy < 0) cy += 513;
            qx = (float)cx; qy = (float)cy;
        }
        n2x[k] = -2.0f * qx;
        n2y[k] = -2.0f * qy;
        q2[k]  = fmaf(qx, qx, qy * qy);
        mn[k]  = 3.4e38f;
    }

    // Stage this split's candidate chunk (SoA; invalid/pad -> sentinel).
    const int base = blockIdx.y * cs;
    for (int i = threadIdx.x; i < csPad; i += BLOCK) {
        int gi = base + i;
        float x = 3.0e4f, y = 3.0e4f;
        if (i < cs && gi < m && fabsf(pts[gi * 5 + 4]) > 0.1f) {
            x = (float)vox[gi * 3 + 1];
            y = (float)vox[gi * 3 + 2];
        }
        sx[i] = x;
        sy[i] = y;
    }
    __syncthreads();

    // 4 candidates/iter via 2x ds_read_b128; packed-pair fp32 math
    // (SLP-vectorizes to v_pk_fma_f32; falls back to scalar fma harmlessly).
    const float4* __restrict__ X4 = (const float4*)sx;
    const float4* __restrict__ Y4 = (const float4*)sy;
    const int iters = csPad >> 2;
#pragma unroll 4
    for (int i = 0; i < iters; ++i) {
        float4 X = X4[i];
        float4 Y = Y4[i];
        float2 X01 = make_float2(X.x, X.y), X23 = make_float2(X.z, X.w);
        float2 Y01 = make_float2(Y.x, Y.y), Y23 = make_float2(Y.z, Y.w);
        float2 C01 = pk_fma2(X01, X01, pk_mul2(Y01, Y01));
        float2 C23 = pk_fma2(X23, X23, pk_mul2(Y23, Y23));
#pragma unroll
        for (int k = 0; k < QPT; ++k) {
            float2 nx = make_float2(n2x[k], n2x[k]);
            float2 ny = make_float2(n2y[k], n2y[k]);
            float2 T01 = pk_fma2(X01, nx, pk_fma2(Y01, ny, C01));
            float2 T23 = pk_fma2(X23, nx, pk_fma2(Y23, ny, C23));
            mn[k] = fminf(fminf(T01.x, T01.y), mn[k]);   // v_min3
            mn[k] = fminf(fminf(T23.x, T23.y), mn[k]);   // v_min3
        }
    }

#pragma unroll
    for (int k = 0; k < QPT; ++k) {
        int q = qbase + k * BLOCK;
        if (q < total) {
            float val = g ? sqrtf(q2[k] + mn[k]) * 0.01f : 0.0f;
            atomicMin(out_bits + q, __float_as_int(val));
        }
    }
}

extern "C" void kernel_launch(void* const* d_in, const int* in_sizes, int n_in,
                              void* d_out, int out_size, void* d_ws, size_t ws_size,
                              hipStream_t stream) {
    const int*   li  = (const int*)d_in[0];
    const int*   ra  = (const int*)d_in[1];
    const float* pts = (const float*)d_in[2];
    const int*   vox = (const int*)d_in[3];

    const int n_li = in_sizes[0] / 2;
    const int n_ra = in_sizes[1] / 2;
    const int m    = in_sizes[2] / 5;

    const int total = (n_li + n_ra) * 9;                            // 92160
    const int qblocks = (total + BLOCK * QPT - 1) / (BLOCK * QPT);  // 45

    const int cs    = (m + SPLITS - 1) / SPLITS;                    // 128
    const int csPad = (cs + 3) & ~3;                                // <= MAXC

    int* gate = (int*)d_ws;
    int* outb = (int*)d_out;

    prep_kernel<<<PREPB, BLOCK, 0, stream>>>(pts, m, gate, outb, total);
    main_kernel<<<dim3(qblocks, SPLITS), BLOCK, 0, stream>>>(
        li, n_li, ra, n_ra, pts, vox, m, cs, csPad, gate, outb, total);
}